// Round 2
// baseline (218.323 us; speedup 1.0000x reference)
//
#include <hip/hip_runtime.h>
#include <stdint.h>

// ---------------------------------------------------------------------------
// VarianceMaximizationCovarianceMinimizationLoss on MI355X
//   features [65536,2,256] fp32, labels [65536] int32 -> scalar fp32 loss
// Pipeline:
//   k_hist    : per-class row counts
//   k_offsets : exclusive prefix -> offsets + scatter cursors
//   k_scatter : counting-sort rows into class-contiguous bf16 array (ws)
//               + fused per-class fp32 column sums
//   k_gram    : per-class partial Grams via mfma_f32_16x16x32_bf16.
//               PARTIAL=1: plain stores, one 256x256 fp32 slab per chunk
//               PARTIAL=0: atomicAdd into S (fallback if ws too small)
//   k_loss*   : sum partials -> cov -> std loss + offdiag^2 loss -> scalar
// ---------------------------------------------------------------------------

#define NCLS  8
#define D     256
#define CHUNK 512
#define SEG   256
#define EPSF  1e-4f
// Hard bound on chunk count: sum_c ceil(n_c/CHUNK) <= nrows/CHUNK + (NCLS-1)
#define TMAX  264

typedef __bf16 bf16x8 __attribute__((ext_vector_type(8)));
typedef float  f32x4  __attribute__((ext_vector_type(4)));

__device__ __forceinline__ unsigned short f2bf(float f) {
    unsigned int x = __float_as_uint(f);
    x += 0x7fffu + ((x >> 16) & 1u);      // round-to-nearest-even
    return (unsigned short)(x >> 16);
}

// ---- k1a: histogram of row counts per class -------------------------------
__global__ void k_hist(const int* __restrict__ labels, int nlab, int vfac,
                       int* __restrict__ counts) {
    __shared__ int lc[NCLS];
    int t = threadIdx.x;
    if (t < NCLS) lc[t] = 0;
    __syncthreads();
    for (int i = blockIdx.x * blockDim.x + t; i < nlab; i += gridDim.x * blockDim.x)
        atomicAdd(&lc[labels[i] & 7], vfac);
    __syncthreads();
    if (t < NCLS && lc[t]) atomicAdd(&counts[t], lc[t]);
}

// ---- k1b: offsets + cursors ----------------------------------------------
__global__ void k_offsets(const int* __restrict__ counts,
                          int* __restrict__ offsets, int* __restrict__ cursor) {
    if (threadIdx.x == 0) {
        int acc = 0;
        for (int c = 0; c < NCLS; ++c) { offsets[c] = acc; cursor[c] = acc; acc += counts[c]; }
    }
}

// ---- k2: scatter rows into class-sorted bf16 + column sums ----------------
__global__ __launch_bounds__(256) void k_scatter(
    const float* __restrict__ X, const int* __restrict__ labels,
    int nrows, int vfac,
    unsigned short* __restrict__ sorted, int* __restrict__ cursor,
    float* __restrict__ gsums)
{
    __shared__ float sumbuf[4][NCLS][D];         // 32 KB, per-wave class sums
    __shared__ int lcnt[NCLS], lbase[NCLS];
    __shared__ short lrank[SEG];
    __shared__ unsigned char lcls[SEG];

    int t  = threadIdx.x;
    int r0 = blockIdx.x * SEG;

    for (int i = t; i < 4 * NCLS * D; i += 256) ((float*)sumbuf)[i] = 0.f;
    if (t < NCLS) lcnt[t] = 0;
    __syncthreads();

    {
        int row = r0 + t;
        if (t < SEG && row < nrows) {
            int c = labels[row / vfac] & 7;
            lcls[t] = (unsigned char)c;
            lrank[t] = (short)atomicAdd(&lcnt[c], 1);
        }
    }
    __syncthreads();
    if (t < NCLS) lbase[t] = lcnt[t] ? atomicAdd(&cursor[t], lcnt[t]) : 0;
    __syncthreads();

    int w = t >> 6, lane = t & 63;
    for (int i = w; i < SEG; i += 4) {
        int row = r0 + i;
        if (row >= nrows) break;
        int c = lcls[i];
        int dest = lbase[c] + lrank[i];
        float4 v = *(const float4*)(X + (size_t)row * D + lane * 4);
        float* sb = &sumbuf[w][c][lane * 4];
        sb[0] += v.x; sb[1] += v.y; sb[2] += v.z; sb[3] += v.w;
        ushort4 o;
        o.x = f2bf(v.x); o.y = f2bf(v.y); o.z = f2bf(v.z); o.w = f2bf(v.w);
        *(ushort4*)(sorted + (size_t)dest * D + lane * 4) = o;
    }
    __syncthreads();

    for (int i = t; i < NCLS * D; i += 256) {
        float s = sumbuf[0][0][i] + sumbuf[1][0][i] + sumbuf[2][0][i] + sumbuf[3][0][i];
        atomicAdd(&gsums[i], s);
    }
}

// ---- k3: per-class partial Grams via MFMA ---------------------------------
// WG = 512 threads (8 waves, 2x4 -> 128x64 per wave), full 256x256 acc.
// LDS K-tile stored transposed: element (c,k) at byte c*128 + (2k ^ ((c&7)<<4))
// PARTIAL=1: out = part buffer, slab per chunk, plain stores.
// PARTIAL=0: out = S, atomicAdd (fallback).
template<int PARTIAL>
__global__ __launch_bounds__(512, 2) void k_gram(
    const unsigned short* __restrict__ sorted,
    const int* __restrict__ counts, const int* __restrict__ offsets,
    float* __restrict__ out)
{
    __shared__ __align__(16) unsigned char lds[64 * 256 * 2];   // 32 KB

    int t = threadIdx.x;
    int lane = t & 63;
    int w = t >> 6;
    int wrow = w >> 2, wcol = w & 3;

    int kblk = t & 15;       // staging: 16 k-blocks of 4 rows
    int cblk = t >> 4;       //          32 col-blocks of 8 cols

    int nch[NCLS], ofch[NCLS];
    int T = 0;
    for (int c = 0; c < NCLS; ++c) {
        int n = counts[c];
        nch[c] = (n + CHUNK - 1) / CHUNK;
        ofch[c] = T;
        T += nch[c];
    }

    for (int item = blockIdx.x; item < T; item += gridDim.x) {
        int c = 0;
        while (c < NCLS - 1 && item >= ofch[c + 1]) ++c;
        int chunk = item - ofch[c];
        int base = offsets[c] + chunk * CHUNK;
        int rows = min(CHUNK, counts[c] - chunk * CHUNK);

        f32x4 acc[8][4];
        #pragma unroll
        for (int i = 0; i < 8; ++i)
            #pragma unroll
            for (int j = 0; j < 4; ++j)
                #pragma unroll
                for (int r = 0; r < 4; ++r) acc[i][j][r] = 0.f;

        int ntiles = (rows + 63) >> 6;

        // prefetch tile 0 into registers
        uint4 R[4];
        {
            int rbase = kblk * 4;
            #pragma unroll
            for (int j = 0; j < 4; ++j) {
                int r = rbase + j;
                R[j] = (r < rows)
                    ? *(const uint4*)(sorted + (((size_t)(base + r)) << 8) + cblk * 8)
                    : make_uint4(0u, 0u, 0u, 0u);
            }
        }

        for (int kt = 0; kt < ntiles; ++kt) {
            __syncthreads();   // LDS free (previous tile's compute done)
            // reg -> LDS transposed (4 rows packed per b64 write)
            #pragma unroll
            for (int cc = 0; cc < 8; ++cc) {
                int wd = cc >> 1;
                int sh = (cc & 1) * 16;
                unsigned int e0 = ((((const unsigned int*)&R[0])[wd]) >> sh) & 0xffffu;
                unsigned int e1 = ((((const unsigned int*)&R[1])[wd]) >> sh) & 0xffffu;
                unsigned int e2 = ((((const unsigned int*)&R[2])[wd]) >> sh) & 0xffffu;
                unsigned int e3 = ((((const unsigned int*)&R[3])[wd]) >> sh) & 0xffffu;
                int ccol = cblk * 8 + cc;
                int byt = ccol * 128 + ((kblk * 8) ^ (cc << 4));
                *(uint2*)(lds + byt) = make_uint2(e0 | (e1 << 16), e2 | (e3 << 16));
            }
            // issue next tile's global loads (latency hides under compute)
            uint4 Rn[4];
            if (kt + 1 < ntiles) {
                int rbase = (kt + 1) * 64 + kblk * 4;
                #pragma unroll
                for (int j = 0; j < 4; ++j) {
                    int r = rbase + j;
                    Rn[j] = (r < rows)
                        ? *(const uint4*)(sorted + (((size_t)(base + r)) << 8) + cblk * 8)
                        : make_uint4(0u, 0u, 0u, 0u);
                }
            } else {
                #pragma unroll
                for (int j = 0; j < 4; ++j) Rn[j] = make_uint4(0u, 0u, 0u, 0u);
            }
            __syncthreads();
            // compute: 2 k-steps of 32
            #pragma unroll
            for (int ks = 0; ks < 2; ++ks) {
                int kb2 = ks * 64 + ((lane >> 4) << 4);
                int swz = (lane & 7) << 4;
                bf16x8 af[8], bfr[4];
                #pragma unroll
                for (int ti = 0; ti < 8; ++ti) {
                    int ccol = wrow * 128 + ti * 16 + (lane & 15);
                    af[ti] = __builtin_bit_cast(bf16x8,
                        *(const uint4*)(lds + ccol * 128 + (kb2 ^ swz)));
                }
                #pragma unroll
                for (int tj = 0; tj < 4; ++tj) {
                    int ccol = wcol * 64 + tj * 16 + (lane & 15);
                    bfr[tj] = __builtin_bit_cast(bf16x8,
                        *(const uint4*)(lds + ccol * 128 + (kb2 ^ swz)));
                }
                #pragma unroll
                for (int ti = 0; ti < 8; ++ti)
                    #pragma unroll
                    for (int tj = 0; tj < 4; ++tj)
                        acc[ti][tj] = __builtin_amdgcn_mfma_f32_16x16x32_bf16(
                            af[ti], bfr[tj], acc[ti][tj], 0, 0, 0);
            }
            #pragma unroll
            for (int j = 0; j < 4; ++j) R[j] = Rn[j];
        }

        // flush (C/D layout: col = lane&15, row = (lane>>4)*4 + r)
        if (PARTIAL) {
            float* dst = out + (size_t)item * (D * D);
            #pragma unroll
            for (int ti = 0; ti < 8; ++ti) {
                int row0 = wrow * 128 + ti * 16 + ((lane >> 4) << 2);
                #pragma unroll
                for (int tj = 0; tj < 4; ++tj) {
                    int col = wcol * 64 + tj * 16 + (lane & 15);
                    #pragma unroll
                    for (int r = 0; r < 4; ++r)
                        dst[(row0 + r) * D + col] = acc[ti][tj][r];
                }
            }
        } else {
            float* Sc = out + (((size_t)c) << 16);
            #pragma unroll
            for (int ti = 0; ti < 8; ++ti) {
                int row0 = wrow * 128 + ti * 16 + ((lane >> 4) << 2);
                #pragma unroll
                for (int tj = 0; tj < 4; ++tj) {
                    int col = wcol * 64 + tj * 16 + (lane & 15);
                    #pragma unroll
                    for (int r = 0; r < 4; ++r)
                        atomicAdd(&Sc[(row0 + r) * D + col], acc[ti][tj][r]);
                }
            }
        }
    }
}

// ---- k4a: loss epilogue from per-chunk partials ---------------------------
__global__ __launch_bounds__(256) void k_loss_part(
    const float* __restrict__ part, const float* __restrict__ gsums,
    const int* __restrict__ counts, float* __restrict__ out)
{
    __shared__ float red[256];
    int t = threadIdx.x;
    int nch[NCLS], ofch[NCLS];
    int T = 0;
    for (int c = 0; c < NCLS; ++c) {
        int n = counts[c];
        nch[c] = (n + CHUNK - 1) / CHUNK;
        ofch[c] = T;
        T += nch[c];
    }
    float local = 0.f;
    const int total = NCLS * D * D;
    for (int idx = blockIdx.x * blockDim.x + t; idx < total; idx += gridDim.x * blockDim.x) {
        int c = idx >> 16;
        int ij = idx & 0xffff;
        int i = ij >> 8, j = ij & 255;
        const float* p = part + (size_t)ofch[c] * (D * D) + ij;
        float s = 0.f;
        for (int q = 0; q < nch[c]; ++q) s += p[(size_t)q * (D * D)];
        float n  = (float)counts[c];
        float mi = gsums[c * D + i] / n;
        float mj = gsums[c * D + j] / n;
        float cov = (s - n * mi * mj) / (n - 1.f);
        float contrib;
        if (i == j) {
            float sd = sqrtf(cov + EPSF);
            contrib = fmaxf(1.f - sd, 0.f) * (1.f / (float)D);
        } else {
            contrib = cov * cov * (1.f / (float)D);
        }
        local += contrib;
    }
    red[t] = local;
    __syncthreads();
    for (int s = 128; s > 0; s >>= 1) {
        if (t < s) red[t] += red[t + s];
        __syncthreads();
    }
    if (t == 0) atomicAdd(out, red[0]);
}

// ---- k4b: loss epilogue from accumulated S (fallback path) ----------------
__global__ __launch_bounds__(256) void k_loss_S(
    const float* __restrict__ S, const float* __restrict__ gsums,
    const int* __restrict__ counts, float* __restrict__ out)
{
    __shared__ float red[256];
    int t = threadIdx.x;
    float local = 0.f;
    const int total = NCLS * D * D;
    for (int idx = blockIdx.x * blockDim.x + t; idx < total; idx += gridDim.x * blockDim.x) {
        int c = idx >> 16;
        int ij = idx & 0xffff;
        int i = ij >> 8, j = ij & 255;
        float n  = (float)counts[c];
        float mi = gsums[c * D + i] / n;
        float mj = gsums[c * D + j] / n;
        float cov = (S[idx] - n * mi * mj) / (n - 1.f);
        float contrib;
        if (i == j) {
            float sd = sqrtf(cov + EPSF);
            contrib = fmaxf(1.f - sd, 0.f) * (1.f / (float)D);
        } else {
            contrib = cov * cov * (1.f / (float)D);
        }
        local += contrib;
    }
    red[t] = local;
    __syncthreads();
    for (int s = 128; s > 0; s >>= 1) {
        if (t < s) red[t] += red[t + s];
        __syncthreads();
    }
    if (t == 0) atomicAdd(out, red[0]);
}

// ---------------------------------------------------------------------------
extern "C" void kernel_launch(void* const* d_in, const int* in_sizes, int n_in,
                              void* d_out, int out_size, void* d_ws, size_t ws_size,
                              hipStream_t stream)
{
    const float* X      = (const float*)d_in[0];
    const int*   labels = (const int*)d_in[1];
    int nfeat = in_sizes[0];
    int nlab  = in_sizes[1];
    int nrows = nfeat / D;            // 131072
    int vfac  = nrows / nlab;         // 2 views per sample

    char* ws = (char*)d_ws;
    size_t sz_sorted = (size_t)nrows * D * 2;            // 67.1 MB bf16
    size_t sz_part   = (size_t)TMAX * D * D * 4;         // 69.2 MB fp32 partials
    size_t sz_S      = (size_t)NCLS * D * D * 4;         // 2 MB
    size_t tail      = 16384;                            // gsums + counters

    // choose path by available scratch (host-side, deterministic)
    bool partial_path = ws_size >= sz_sorted + sz_part + tail;

    size_t off_big   = sz_sorted;                        // part OR S
    size_t sz_big    = partial_path ? sz_part : sz_S;
    size_t off_sums  = off_big + sz_big;
    size_t sz_sums   = (size_t)NCLS * D * 4;             // 8 KB
    size_t off_cnt   = off_sums + sz_sums;
    size_t off_ofs   = off_cnt + 64;
    size_t off_cur   = off_ofs + 64;

    unsigned short* sorted  = (unsigned short*)(ws);
    float*          big     = (float*)(ws + off_big);    // part or S
    float*          gsums   = (float*)(ws + off_sums);
    int*            counts  = (int*)(ws + off_cnt);
    int*            offsets = (int*)(ws + off_ofs);
    int*            cursor  = (int*)(ws + off_cur);

    if (!partial_path)
        hipMemsetAsync(big, 0, sz_S, stream);            // S must start at 0
    hipMemsetAsync(gsums, 0, sz_sums, stream);
    hipMemsetAsync(counts, 0, 64, stream);
    hipMemsetAsync(d_out, 0, (size_t)out_size * sizeof(float), stream);

    k_hist<<<64, 256, 0, stream>>>(labels, nlab, vfac, counts);
    k_offsets<<<1, 64, 0, stream>>>(counts, offsets, cursor);
    k_scatter<<<(nrows + SEG - 1) / SEG, 256, 0, stream>>>(
        X, labels, nrows, vfac, sorted, cursor, gsums);
    if (partial_path) {
        k_gram<1><<<256, 512, 0, stream>>>(sorted, counts, offsets, big);
        k_loss_part<<<512, 256, 0, stream>>>(big, gsums, counts, (float*)d_out);
    } else {
        k_gram<0><<<256, 512, 0, stream>>>(sorted, counts, offsets, big);
        k_loss_S<<<512, 256, 0, stream>>>(big, gsums, counts, (float*)d_out);
    }
}

// Round 3
// 197.066 us; speedup vs baseline: 1.1079x; 1.1079x over previous
//
#include <hip/hip_runtime.h>
#include <stdint.h>

// ---------------------------------------------------------------------------
// VarianceMaximizationCovarianceMinimizationLoss on MI355X
//   features [65536,2,256] fp32, labels [65536] int32 -> scalar fp32 loss
// Pipeline (round 3: index-gather, no sorted copy, no atomic Gram flush):
//   k_hist    : per-class row counts
//   k_offsets : exclusive prefix -> offsets + cursors
//   k_idx     : class-sorted row-index array (0.5 MB)
//   k_gram_g  : per-chunk (single-class, 1024 rows) Gram via
//               mfma_f32_16x16x32_bf16, gathering fp32 rows from X,
//               converting to bf16 in-reg, staging to conflict-free
//               XOR-swizzled LDS. Plain-store flush to partial slabs.
//               Fused fp32 per-chunk column sums.
//   k_gsum    : reduce per-chunk column sums -> per-class sums
//   k_loss    : sum partial Grams -> cov -> std loss + offdiag^2 -> scalar
// ---------------------------------------------------------------------------

#define NCLS  8
#define D     256
#define CHUNK 1024
#define SEG   256
#define EPSF  1e-4f
// sum_c ceil(n_c/CHUNK) <= nrows/CHUNK + NCLS-1 = 128+7 = 135
#define TMAX  144

typedef __bf16 bf16x8 __attribute__((ext_vector_type(8)));
typedef float  f32x4  __attribute__((ext_vector_type(4)));

__device__ __forceinline__ unsigned short f2bf(float f) {
    unsigned int x = __float_as_uint(f);
    x += 0x7fffu + ((x >> 16) & 1u);      // round-to-nearest-even
    return (unsigned short)(x >> 16);
}

// ---- k1a: histogram of row counts per class -------------------------------
__global__ void k_hist(const int* __restrict__ labels, int nlab, int vfac,
                       int* __restrict__ counts) {
    __shared__ int lc[NCLS];
    int t = threadIdx.x;
    if (t < NCLS) lc[t] = 0;
    __syncthreads();
    for (int i = blockIdx.x * blockDim.x + t; i < nlab; i += gridDim.x * blockDim.x)
        atomicAdd(&lc[labels[i] & 7], vfac);
    __syncthreads();
    if (t < NCLS && lc[t]) atomicAdd(&counts[t], lc[t]);
}

// ---- k1b: offsets + cursors ----------------------------------------------
__global__ void k_offsets(const int* __restrict__ counts,
                          int* __restrict__ offsets, int* __restrict__ cursor) {
    if (threadIdx.x == 0) {
        int acc = 0;
        for (int c = 0; c < NCLS; ++c) { offsets[c] = acc; cursor[c] = acc; acc += counts[c]; }
    }
}

// ---- k2: class-sorted row-index array -------------------------------------
__global__ __launch_bounds__(256) void k_idx(
    const int* __restrict__ labels, int nrows, int vfac,
    int* __restrict__ cursor, int* __restrict__ idx)
{
    __shared__ int lcnt[NCLS], lbase[NCLS];
    int t = threadIdx.x;
    int row = blockIdx.x * SEG + t;
    if (t < NCLS) lcnt[t] = 0;
    __syncthreads();
    int c = 0, rk = 0;
    bool ok = (row < nrows);
    if (ok) {
        c = labels[row / vfac] & 7;
        rk = atomicAdd(&lcnt[c], 1);
    }
    __syncthreads();
    if (t < NCLS) lbase[t] = lcnt[t] ? atomicAdd(&cursor[t], lcnt[t]) : 0;
    __syncthreads();
    if (ok) idx[lbase[c] + rk] = row;
}

// ---- k3: per-chunk Gram via MFMA, gathered from fp32 X --------------------
// WG = 512 threads (8 waves as 2x4 -> each wave owns 128x64 of the 256x256).
// LDS K-tile (64 rows x 256 cols) stored transposed: element (ccol,k) at byte
//   ccol*128 + ((k&~3)*2 ^ ((ccol&7)<<4))   [4 rows packed per 8B, as r1/r2]
// Staging: thread (kblk=t&15, cblk=t>>4) owns rows kblk*4..+3, cols cblk*8..+7.
__global__ __launch_bounds__(512, 2) void k_gram_g(
    const float* __restrict__ X, const int* __restrict__ idx,
    const int* __restrict__ counts, const int* __restrict__ offsets,
    float* __restrict__ part, float* __restrict__ csums)
{
    __shared__ __align__(16) unsigned char lds[64 * 256 * 2];   // 32 KB

    int t = threadIdx.x;
    int lane = t & 63;
    int w = t >> 6;
    int wrow = w >> 2, wcol = w & 3;
    int kblk = t & 15;
    int cblk = t >> 4;

    int nch[NCLS], ofch[NCLS];
    int T = 0;
    for (int c = 0; c < NCLS; ++c) {
        int n = counts[c];
        nch[c] = (n + CHUNK - 1) / CHUNK;
        ofch[c] = T;
        T += nch[c];
    }

    for (int item = blockIdx.x; item < T; item += gridDim.x) {
        int c = 0;
        while (c < NCLS - 1 && item >= ofch[c + 1]) ++c;
        int chunk = item - ofch[c];
        int base = offsets[c] + chunk * CHUNK;
        int rows = min(CHUNK, counts[c] - chunk * CHUNK);

        f32x4 acc[8][4];
        #pragma unroll
        for (int i = 0; i < 8; ++i)
            #pragma unroll
            for (int j = 0; j < 4; ++j)
                #pragma unroll
                for (int r = 0; r < 4; ++r) acc[i][j][r] = 0.f;
        float sumv[8];
        #pragma unroll
        for (int q = 0; q < 8; ++q) sumv[q] = 0.f;

        int ntiles = (rows + 63) >> 6;
        const f32x4 zf = {0.f, 0.f, 0.f, 0.f};

        // prologue: gather tile 0 into regs (fp32)
        f32x4 F[8];
        {
            int rb = kblk * 4;
            #pragma unroll
            for (int j = 0; j < 4; ++j) {
                int r = rb + j;
                if (r < rows) {
                    int rid = idx[base + r];
                    const float* rp = X + ((size_t)rid << 8) + cblk * 8;
                    F[j * 2]     = *(const f32x4*)rp;
                    F[j * 2 + 1] = *(const f32x4*)(rp + 4);
                } else {
                    F[j * 2] = zf; F[j * 2 + 1] = zf;
                }
            }
        }

        for (int kt = 0; kt < ntiles; ++kt) {
            __syncthreads();           // previous tile's LDS reads done
            // fused fp32 column sums from staging regs
            #pragma unroll
            for (int j = 0; j < 4; ++j)
                #pragma unroll
                for (int q = 0; q < 4; ++q) {
                    sumv[q]     += F[j * 2][q];
                    sumv[4 + q] += F[j * 2 + 1][q];
                }
            // convert + transposed swizzled LDS write (4 rows packed per 8B)
            #pragma unroll
            for (int cc = 0; cc < 8; ++cc) {
                unsigned int e0 = f2bf(F[0 + (cc >> 2)][cc & 3]);
                unsigned int e1 = f2bf(F[2 + (cc >> 2)][cc & 3]);
                unsigned int e2 = f2bf(F[4 + (cc >> 2)][cc & 3]);
                unsigned int e3 = f2bf(F[6 + (cc >> 2)][cc & 3]);
                int ccol = cblk * 8 + cc;
                int byt = ccol * 128 + ((kblk * 8) ^ (cc << 4));
                *(uint2*)(lds + byt) = make_uint2(e0 | (e1 << 16), e2 | (e3 << 16));
            }
            // prefetch next tile into F (latency spans barrier + MFMA phase)
            if (kt + 1 < ntiles) {
                int rb = (kt + 1) * 64 + kblk * 4;
                #pragma unroll
                for (int j = 0; j < 4; ++j) {
                    int r = rb + j;
                    if (r < rows) {
                        int rid = idx[base + r];
                        const float* rp = X + ((size_t)rid << 8) + cblk * 8;
                        F[j * 2]     = *(const f32x4*)rp;
                        F[j * 2 + 1] = *(const f32x4*)(rp + 4);
                    } else {
                        F[j * 2] = zf; F[j * 2 + 1] = zf;
                    }
                }
            }
            __syncthreads();
            // compute: 2 k-steps of 32 (proven conflict-free read pattern)
            #pragma unroll
            for (int ks = 0; ks < 2; ++ks) {
                int kb2 = ks * 64 + ((lane >> 4) << 4);
                int swz = (lane & 7) << 4;
                bf16x8 af[8], bfr[4];
                #pragma unroll
                for (int ti = 0; ti < 8; ++ti) {
                    int ccol = wrow * 128 + ti * 16 + (lane & 15);
                    af[ti] = __builtin_bit_cast(bf16x8,
                        *(const uint4*)(lds + ccol * 128 + (kb2 ^ swz)));
                }
                #pragma unroll
                for (int tj = 0; tj < 4; ++tj) {
                    int ccol = wcol * 64 + tj * 16 + (lane & 15);
                    bfr[tj] = __builtin_bit_cast(bf16x8,
                        *(const uint4*)(lds + ccol * 128 + (kb2 ^ swz)));
                }
                #pragma unroll
                for (int ti = 0; ti < 8; ++ti)
                    #pragma unroll
                    for (int tj = 0; tj < 4; ++tj)
                        acc[ti][tj] = __builtin_amdgcn_mfma_f32_16x16x32_bf16(
                            af[ti], bfr[tj], acc[ti][tj], 0, 0, 0);
            }
        }

        // flush partial Gram: plain stores (C/D: col=lane&15, row=(lane>>4)*4+r)
        float* dst = part + (size_t)item * (D * D);
        #pragma unroll
        for (int ti = 0; ti < 8; ++ti) {
            int row0 = wrow * 128 + ti * 16 + ((lane >> 4) << 2);
            #pragma unroll
            for (int tj = 0; tj < 4; ++tj) {
                int col = wcol * 64 + tj * 16 + (lane & 15);
                #pragma unroll
                for (int r = 0; r < 4; ++r)
                    dst[(row0 + r) * D + col] = acc[ti][tj][r];
            }
        }

        // per-chunk column sums: reduce over the 16 kblk-threads (contiguous
        // 16-lane groups -> shfl_xor 1,2,4,8 stays within the group)
        #pragma unroll
        for (int s = 1; s < 16; s <<= 1)
            #pragma unroll
            for (int q = 0; q < 8; ++q)
                sumv[q] += __shfl_xor(sumv[q], s, 64);
        if ((t & 15) == 0) {
            float* cs = csums + (size_t)item * D + cblk * 8;
            #pragma unroll
            for (int q = 0; q < 8; ++q) cs[q] = sumv[q];
        }
    }
}

// ---- k4: reduce per-chunk column sums -> per-class sums -------------------
__global__ __launch_bounds__(256) void k_gsum(
    const float* __restrict__ csums, const int* __restrict__ counts,
    float* __restrict__ gsums)
{
    int c = blockIdx.x;
    int i = threadIdx.x;
    int of = 0;
    for (int cc = 0; cc < c; ++cc) of += (counts[cc] + CHUNK - 1) / CHUNK;
    int nc = (counts[c] + CHUNK - 1) / CHUNK;
    float s = 0.f;
    for (int q = 0; q < nc; ++q) s += csums[(size_t)(of + q) * D + i];
    gsums[c * D + i] = s;
}

// ---- k5: loss epilogue from per-chunk partial Grams -----------------------
__global__ __launch_bounds__(256) void k_loss(
    const float* __restrict__ part, const float* __restrict__ gsums,
    const int* __restrict__ counts, float* __restrict__ out)
{
    __shared__ float red[256];
    int t = threadIdx.x;
    int nch[NCLS], ofch[NCLS];
    int T = 0;
    for (int c = 0; c < NCLS; ++c) {
        int n = counts[c];
        nch[c] = (n + CHUNK - 1) / CHUNK;
        ofch[c] = T;
        T += nch[c];
    }
    float local = 0.f;
    const int total = NCLS * D * D;
    for (int idx = blockIdx.x * blockDim.x + t; idx < total; idx += gridDim.x * blockDim.x) {
        int c = idx >> 16;
        int ij = idx & 0xffff;
        int i = ij >> 8, j = ij & 255;
        const float* p = part + (size_t)ofch[c] * (D * D) + ij;
        float s = 0.f;
        for (int q = 0; q < nch[c]; ++q) s += p[(size_t)q * (D * D)];
        float n  = (float)counts[c];
        float mi = gsums[c * D + i] / n;
        float mj = gsums[c * D + j] / n;
        float cov = (s - n * mi * mj) / (n - 1.f);
        float contrib;
        if (i == j) {
            float sd = sqrtf(cov + EPSF);
            contrib = fmaxf(1.f - sd, 0.f) * (1.f / (float)D);
        } else {
            contrib = cov * cov * (1.f / (float)D);
        }
        local += contrib;
    }
    red[t] = local;
    __syncthreads();
    for (int s = 128; s > 0; s >>= 1) {
        if (t < s) red[t] += red[t + s];
        __syncthreads();
    }
    if (t == 0) atomicAdd(out, red[0]);
}

// ---------------------------------------------------------------------------
extern "C" void kernel_launch(void* const* d_in, const int* in_sizes, int n_in,
                              void* d_out, int out_size, void* d_ws, size_t ws_size,
                              hipStream_t stream)
{
    const float* X      = (const float*)d_in[0];
    const int*   labels = (const int*)d_in[1];
    int nfeat = in_sizes[0];
    int nlab  = in_sizes[1];
    int nrows = nfeat / D;            // 131072
    int vfac  = nrows / nlab;         // 2 views per sample

    char* ws = (char*)d_ws;
    size_t off_idx   = 0;
    size_t sz_idx    = (size_t)nrows * 4;                 // 512 KB
    size_t off_part  = (off_idx + sz_idx + 255) & ~(size_t)255;
    size_t sz_part   = (size_t)TMAX * D * D * 4;          // 37.7 MB
    size_t off_cs    = (off_part + sz_part + 255) & ~(size_t)255;
    size_t sz_cs     = (size_t)TMAX * D * 4;              // 147 KB
    size_t off_gs    = (off_cs + sz_cs + 255) & ~(size_t)255;
    size_t sz_gs     = (size_t)NCLS * D * 4;              // 8 KB
    size_t off_cnt   = (off_gs + sz_gs + 255) & ~(size_t)255;
    size_t off_ofs   = off_cnt + 64;
    size_t off_cur   = off_ofs + 64;

    int*   idx     = (int*)(ws + off_idx);
    float* part    = (float*)(ws + off_part);
    float* csums   = (float*)(ws + off_cs);
    float* gsums   = (float*)(ws + off_gs);
    int*   counts  = (int*)(ws + off_cnt);
    int*   offsets = (int*)(ws + off_ofs);
    int*   cursor  = (int*)(ws + off_cur);

    hipMemsetAsync(counts, 0, 64, stream);
    hipMemsetAsync(d_out, 0, (size_t)out_size * sizeof(float), stream);

    k_hist<<<64, 256, 0, stream>>>(labels, nlab, vfac, counts);
    k_offsets<<<1, 64, 0, stream>>>(counts, offsets, cursor);
    k_idx<<<(nrows + SEG - 1) / SEG, SEG, 0, stream>>>(labels, nrows, vfac, cursor, idx);
    k_gram_g<<<TMAX, 512, 0, stream>>>(X, idx, counts, offsets, part, csums);
    k_gsum<<<NCLS, 256, 0, stream>>>(csums, counts, gsums);
    k_loss<<<512, 256, 0, stream>>>(part, gsums, counts, (float*)d_out);
}

// Round 4
// 165.196 us; speedup vs baseline: 1.3216x; 1.1929x over previous
//
#include <hip/hip_runtime.h>
#include <stdint.h>

// ---------------------------------------------------------------------------
// VarianceMaximizationCovarianceMinimizationLoss on MI355X
//   features [65536,2,256] fp32, labels [65536] int32 -> scalar fp32 loss
// Round 4: gather-Gram, spill-free + load-overlap fix.
//   k_hist    : per-class row counts
//   k_offsets : exclusive prefix -> offsets + cursors
//   k_idx     : class-sorted row-index array (0.5 MB)
//   k_gram_g  : per-chunk (1024 rows, single class) Gram via
//               mfma_f32_16x16x32_bf16. fp32 rows gathered from X, converted
//               to packed bf16 (R[4], 16 VGPR) immediately; X loads issued
//               AFTER the barrier so they fly under the MFMA phase.
//               Plain-store flush to partial slabs. Fused column sums.
//   k_gsum    : reduce per-chunk column sums -> per-class sums
//   k_loss    : sum partial Grams -> cov -> std loss + offdiag^2 -> scalar
// ---------------------------------------------------------------------------

#define NCLS  8
#define D     256
#define CHUNK 1024
#define SEG   256
#define EPSF  1e-4f
// sum_c ceil(n_c/CHUNK) <= nrows/CHUNK + NCLS-1 = 128+7 = 135
#define TMAX  144

typedef __bf16 bf16x8 __attribute__((ext_vector_type(8)));
typedef float  f32x4  __attribute__((ext_vector_type(4)));

__device__ __forceinline__ unsigned short f2bf(float f) {
    unsigned int x = __float_as_uint(f);
    x += 0x7fffu + ((x >> 16) & 1u);      // round-to-nearest-even
    return (unsigned short)(x >> 16);
}

// ---- k1a: histogram of row counts per class -------------------------------
__global__ void k_hist(const int* __restrict__ labels, int nlab, int vfac,
                       int* __restrict__ counts) {
    __shared__ int lc[NCLS];
    int t = threadIdx.x;
    if (t < NCLS) lc[t] = 0;
    __syncthreads();
    for (int i = blockIdx.x * blockDim.x + t; i < nlab; i += gridDim.x * blockDim.x)
        atomicAdd(&lc[labels[i] & 7], vfac);
    __syncthreads();
    if (t < NCLS && lc[t]) atomicAdd(&counts[t], lc[t]);
}

// ---- k1b: offsets + cursors ----------------------------------------------
__global__ void k_offsets(const int* __restrict__ counts,
                          int* __restrict__ offsets, int* __restrict__ cursor) {
    if (threadIdx.x == 0) {
        int acc = 0;
        for (int c = 0; c < NCLS; ++c) { offsets[c] = acc; cursor[c] = acc; acc += counts[c]; }
    }
}

// ---- k2: class-sorted row-index array -------------------------------------
__global__ __launch_bounds__(256) void k_idx(
    const int* __restrict__ labels, int nrows, int vfac,
    int* __restrict__ cursor, int* __restrict__ idx)
{
    __shared__ int lcnt[NCLS], lbase[NCLS];
    int t = threadIdx.x;
    int row = blockIdx.x * SEG + t;
    if (t < NCLS) lcnt[t] = 0;
    __syncthreads();
    int c = 0, rk = 0;
    bool ok = (row < nrows);
    if (ok) {
        c = labels[row / vfac] & 7;
        rk = atomicAdd(&lcnt[c], 1);
    }
    __syncthreads();
    if (t < NCLS) lbase[t] = lcnt[t] ? atomicAdd(&cursor[t], lcnt[t]) : 0;
    __syncthreads();
    if (ok) idx[lbase[c] + rk] = row;
}

// ---- k3: per-chunk Gram via MFMA, gathered from fp32 X --------------------
// WG = 512 threads (8 waves as 2x4 -> each wave owns 128x64 of the 256x256).
// LDS K-tile (64 k-rows x 256 feature-cols) stored transposed:
//   element (ccol, k) quad packed at byte ccol*128 + ((kquad*8) ^ ((ccol&7)<<4))
// Staging thread (kblk = t&15, cblk = t>>4) owns k-rows kblk*4..+3,
// cols cblk*8..+7. Proven conflict-free (round-3 SQ_LDS_BANK_CONFLICT = 0).
__global__ __launch_bounds__(512, 2) void k_gram_g(
    const float* __restrict__ X, const int* __restrict__ idx,
    const int* __restrict__ counts, const int* __restrict__ offsets,
    float* __restrict__ part, float* __restrict__ csums)
{
    __shared__ __align__(16) unsigned char lds[64 * 256 * 2];   // 32 KB

    int t = threadIdx.x;
    int lane = t & 63;
    int w = t >> 6;
    int wrow = w >> 2, wcol = w & 3;
    int kblk = t & 15;
    int cblk = t >> 4;

    int nch[NCLS], ofch[NCLS];
    int T = 0;
    for (int c = 0; c < NCLS; ++c) {
        int n = counts[c];
        nch[c] = (n + CHUNK - 1) / CHUNK;
        ofch[c] = T;
        T += nch[c];
    }

    const f32x4 zf = {0.f, 0.f, 0.f, 0.f};

    for (int item = blockIdx.x; item < T; item += gridDim.x) {
        int c = 0;
        while (c < NCLS - 1 && item >= ofch[c + 1]) ++c;
        int chunk = item - ofch[c];
        int base = offsets[c] + chunk * CHUNK;
        int rows = min(CHUNK, counts[c] - chunk * CHUNK);
        int ntiles = (rows + 63) >> 6;

        f32x4 acc[8][4];
        #pragma unroll
        for (int i = 0; i < 8; ++i)
            #pragma unroll
            for (int j = 0; j < 4; ++j)
                #pragma unroll
                for (int r = 0; r < 4; ++r) acc[i][j][r] = 0.f;
        float sumv[8];
        #pragma unroll
        for (int q = 0; q < 8; ++q) sumv[q] = 0.f;

        uint4 R[4];        // packed bf16, tile kt (4 rows x 8 cols / thread)
        f32x4 fa[4], fb[4];
        int idn[4];        // row ids for the NEXT tile to be issued

        // ---- prologue: tile 0 ids -> X loads -> convert; ids for tile 1 ---
        #pragma unroll
        for (int j = 0; j < 4; ++j) {
            int r = kblk * 4 + j;
            idn[j] = (r < rows) ? idx[base + r] : 0;
        }
        #pragma unroll
        for (int j = 0; j < 4; ++j) {
            int r = kblk * 4 + j;
            if (r < rows) {
                const float* rp = X + ((size_t)idn[j] << 8) + cblk * 8;
                fa[j] = *(const f32x4*)rp;
                fb[j] = *(const f32x4*)(rp + 4);
            } else { fa[j] = zf; fb[j] = zf; }
        }
        #pragma unroll
        for (int j = 0; j < 4; ++j) {
            int r = 64 + kblk * 4 + j;
            idn[j] = (r < rows) ? idx[base + r] : 0;
        }
        #pragma unroll
        for (int j = 0; j < 4; ++j) {
            #pragma unroll
            for (int q = 0; q < 4; ++q) { sumv[q] += fa[j][q]; sumv[4 + q] += fb[j][q]; }
            unsigned int w0 = (unsigned int)f2bf(fa[j][0]) | ((unsigned int)f2bf(fa[j][1]) << 16);
            unsigned int w1 = (unsigned int)f2bf(fa[j][2]) | ((unsigned int)f2bf(fa[j][3]) << 16);
            unsigned int w2 = (unsigned int)f2bf(fb[j][0]) | ((unsigned int)f2bf(fb[j][1]) << 16);
            unsigned int w3 = (unsigned int)f2bf(fb[j][2]) | ((unsigned int)f2bf(fb[j][3]) << 16);
            R[j] = make_uint4(w0, w1, w2, w3);
        }

        for (int kt = 0; kt < ntiles; ++kt) {
            __syncthreads();           // previous tile's LDS reads done
            // R -> LDS transposed (4 k-rows packed per 8B write)
            #pragma unroll
            for (int cc = 0; cc < 8; ++cc) {
                int wd = cc >> 1;
                int sh = (cc & 1) * 16;
                unsigned int e0 = (((const unsigned int*)&R[0])[wd] >> sh) & 0xffffu;
                unsigned int e1 = (((const unsigned int*)&R[1])[wd] >> sh) & 0xffffu;
                unsigned int e2 = (((const unsigned int*)&R[2])[wd] >> sh) & 0xffffu;
                unsigned int e3 = (((const unsigned int*)&R[3])[wd] >> sh) & 0xffffu;
                int ccol = cblk * 8 + cc;
                int byt = ccol * 128 + ((kblk * 8) ^ (cc << 4));
                *(uint2*)(lds + byt) = make_uint2(e0 | (e1 << 16), e2 | (e3 << 16));
            }
            __syncthreads();           // staging visible

            // issue NEXT tile's X loads AFTER the barrier: they stay in
            // flight under the MFMA phase (first use = convert, below)
            bool more = (kt + 1 < ntiles);
            if (more) {
                #pragma unroll
                for (int j = 0; j < 4; ++j) {
                    int r = (kt + 1) * 64 + kblk * 4 + j;
                    if (r < rows) {
                        const float* rp = X + ((size_t)idn[j] << 8) + cblk * 8;
                        fa[j] = *(const f32x4*)rp;
                        fb[j] = *(const f32x4*)(rp + 4);
                    } else { fa[j] = zf; fb[j] = zf; }
                }
            }
            // ids for tile kt+2 (L2-resident, consumed next iteration)
            int idf[4];
            #pragma unroll
            for (int j = 0; j < 4; ++j) {
                int r = (kt + 2) * 64 + kblk * 4 + j;
                idf[j] = (more && r < rows) ? idx[base + r] : 0;
            }

            // MFMA: 2 k-steps of 32; af loaded per-ti to cap VGPR pressure
            #pragma unroll
            for (int ks = 0; ks < 2; ++ks) {
                int kb2 = ks * 64 + ((lane >> 4) << 4);
                int swz = (lane & 7) << 4;
                bf16x8 bfr[4];
                #pragma unroll
                for (int tj = 0; tj < 4; ++tj) {
                    int ccol = wcol * 64 + tj * 16 + (lane & 15);
                    bfr[tj] = __builtin_bit_cast(bf16x8,
                        *(const uint4*)(lds + ccol * 128 + (kb2 ^ swz)));
                }
                #pragma unroll
                for (int ti = 0; ti < 8; ++ti) {
                    int ccol = wrow * 128 + ti * 16 + (lane & 15);
                    bf16x8 af = __builtin_bit_cast(bf16x8,
                        *(const uint4*)(lds + ccol * 128 + (kb2 ^ swz)));
                    #pragma unroll
                    for (int tj = 0; tj < 4; ++tj)
                        acc[ti][tj] = __builtin_amdgcn_mfma_f32_16x16x32_bf16(
                            af, bfr[tj], acc[ti][tj], 0, 0, 0);
                }
            }

            // convert next tile (waits for the in-flight loads here) + sums
            if (more) {
                #pragma unroll
                for (int j = 0; j < 4; ++j) {
                    #pragma unroll
                    for (int q = 0; q < 4; ++q) { sumv[q] += fa[j][q]; sumv[4 + q] += fb[j][q]; }
                    unsigned int w0 = (unsigned int)f2bf(fa[j][0]) | ((unsigned int)f2bf(fa[j][1]) << 16);
                    unsigned int w1 = (unsigned int)f2bf(fa[j][2]) | ((unsigned int)f2bf(fa[j][3]) << 16);
                    unsigned int w2 = (unsigned int)f2bf(fb[j][0]) | ((unsigned int)f2bf(fb[j][1]) << 16);
                    unsigned int w3 = (unsigned int)f2bf(fb[j][2]) | ((unsigned int)f2bf(fb[j][3]) << 16);
                    R[j] = make_uint4(w0, w1, w2, w3);
                }
                #pragma unroll
                for (int j = 0; j < 4; ++j) idn[j] = idf[j];
            }
        }

        // flush partial Gram: plain stores (C/D: col=lane&15, row=(lane>>4)*4+r)
        float* dst = part + (size_t)item * (D * D);
        #pragma unroll
        for (int ti = 0; ti < 8; ++ti) {
            int row0 = wrow * 128 + ti * 16 + ((lane >> 4) << 2);
            #pragma unroll
            for (int tj = 0; tj < 4; ++tj) {
                int col = wcol * 64 + tj * 16 + (lane & 15);
                #pragma unroll
                for (int r = 0; r < 4; ++r)
                    dst[(row0 + r) * D + col] = acc[ti][tj][r];
            }
        }

        // per-chunk column sums: reduce over the 16 kblk-threads
        #pragma unroll
        for (int s = 1; s < 16; s <<= 1)
            #pragma unroll
            for (int q = 0; q < 8; ++q)
                sumv[q] += __shfl_xor(sumv[q], s, 64);
        if ((t & 15) == 0) {
            float* cs = csums + (size_t)item * D + cblk * 8;
            #pragma unroll
            for (int q = 0; q < 8; ++q) cs[q] = sumv[q];
        }
    }
}

// ---- k4: reduce per-chunk column sums -> per-class sums -------------------
__global__ __launch_bounds__(256) void k_gsum(
    const float* __restrict__ csums, const int* __restrict__ counts,
    float* __restrict__ gsums)
{
    int c = blockIdx.x;
    int i = threadIdx.x;
    int of = 0;
    for (int cc = 0; cc < c; ++cc) of += (counts[cc] + CHUNK - 1) / CHUNK;
    int nc = (counts[c] + CHUNK - 1) / CHUNK;
    float s = 0.f;
    for (int q = 0; q < nc; ++q) s += csums[(size_t)(of + q) * D + i];
    gsums[c * D + i] = s;
}

// ---- k5: loss epilogue from per-chunk partial Grams -----------------------
__global__ __launch_bounds__(256) void k_loss(
    const float* __restrict__ part, const float* __restrict__ gsums,
    const int* __restrict__ counts, float* __restrict__ out)
{
    __shared__ float red[256];
    int t = threadIdx.x;
    int nch[NCLS], ofch[NCLS];
    int T = 0;
    for (int c = 0; c < NCLS; ++c) {
        int n = counts[c];
        nch[c] = (n + CHUNK - 1) / CHUNK;
        ofch[c] = T;
        T += nch[c];
    }
    float local = 0.f;
    const int total = NCLS * D * D;
    for (int idx = blockIdx.x * blockDim.x + t; idx < total; idx += gridDim.x * blockDim.x) {
        int c = idx >> 16;
        int ij = idx & 0xffff;
        int i = ij >> 8, j = ij & 255;
        const float* p = part + (size_t)ofch[c] * (D * D) + ij;
        float s = 0.f;
        for (int q = 0; q < nch[c]; ++q) s += p[(size_t)q * (D * D)];
        float n  = (float)counts[c];
        float mi = gsums[c * D + i] / n;
        float mj = gsums[c * D + j] / n;
        float cov = (s - n * mi * mj) / (n - 1.f);
        float contrib;
        if (i == j) {
            float sd = sqrtf(cov + EPSF);
            contrib = fmaxf(1.f - sd, 0.f) * (1.f / (float)D);
        } else {
            contrib = cov * cov * (1.f / (float)D);
        }
        local += contrib;
    }
    red[t] = local;
    __syncthreads();
    for (int s = 128; s > 0; s >>= 1) {
        if (t < s) red[t] += red[t + s];
        __syncthreads();
    }
    if (t == 0) atomicAdd(out, red[0]);
}

// ---------------------------------------------------------------------------
extern "C" void kernel_launch(void* const* d_in, const int* in_sizes, int n_in,
                              void* d_out, int out_size, void* d_ws, size_t ws_size,
                              hipStream_t stream)
{
    const float* X      = (const float*)d_in[0];
    const int*   labels = (const int*)d_in[1];
    int nfeat = in_sizes[0];
    int nlab  = in_sizes[1];
    int nrows = nfeat / D;            // 131072
    int vfac  = nrows / nlab;         // 2 views per sample

    char* ws = (char*)d_ws;
    size_t off_idx   = 0;
    size_t sz_idx    = (size_t)nrows * 4;                 // 512 KB
    size_t off_part  = (off_idx + sz_idx + 255) & ~(size_t)255;
    size_t sz_part   = (size_t)TMAX * D * D * 4;          // 37.7 MB
    size_t off_cs    = (off_part + sz_part + 255) & ~(size_t)255;
    size_t sz_cs     = (size_t)TMAX * D * 4;              // 147 KB
    size_t off_gs    = (off_cs + sz_cs + 255) & ~(size_t)255;
    size_t sz_gs     = (size_t)NCLS * D * 4;              // 8 KB
    size_t off_cnt   = (off_gs + sz_gs + 255) & ~(size_t)255;
    size_t off_ofs   = off_cnt + 64;
    size_t off_cur   = off_ofs + 64;

    int*   idx     = (int*)(ws + off_idx);
    float* part    = (float*)(ws + off_part);
    float* csums   = (float*)(ws + off_cs);
    float* gsums   = (float*)(ws + off_gs);
    int*   counts  = (int*)(ws + off_cnt);
    int*   offsets = (int*)(ws + off_ofs);
    int*   cursor  = (int*)(ws + off_cur);

    hipMemsetAsync(counts, 0, 64, stream);
    hipMemsetAsync(d_out, 0, (size_t)out_size * sizeof(float), stream);

    k_hist<<<64, 256, 0, stream>>>(labels, nlab, vfac, counts);
    k_offsets<<<1, 64, 0, stream>>>(counts, offsets, cursor);
    k_idx<<<(nrows + SEG - 1) / SEG, SEG, 0, stream>>>(labels, nrows, vfac, cursor, idx);
    k_gram_g<<<TMAX, 512, 0, stream>>>(X, idx, counts, offsets, part, csums);
    k_gsum<<<NCLS, 256, 0, stream>>>(csums, counts, gsums);
    k_loss<<<512, 256, 0, stream>>>(part, gsums, counts, (float*)d_out);
}

// Round 5
// 134.035 us; speedup vs baseline: 1.6289x; 1.2325x over previous
//
#include <hip/hip_runtime.h>
#include <stdint.h>

// ---------------------------------------------------------------------------
// VarianceMaximizationCovarianceMinimizationLoss on MI355X
//   features [65536,2,256] fp32, labels [65536] int32 -> scalar fp32 loss
// Round 5: gather-Gram with column-split (acc=64 regs) -> spill-free + TLP.
//   k_hist    : per-class row counts
//   k_offsets : exclusive prefix -> offsets + cursors
//   k_idx     : class-sorted row-index array (0.5 MB)
//   k_gram_g  : per-(chunk, col-half) partial Gram via mfma 16x16x32 bf16.
//               Each WG: 256 rows x 128 cols of one chunk's Gram.
//               Gather fp32 rows from X, convert, stage transposed+swizzled
//               LDS (validated layout). Plain-store flush. Fused col sums.
//   k_gsum    : reduce per-chunk column sums -> per-class sums
//   k_loss    : sum partial Grams -> cov -> std loss + offdiag^2 -> scalar
// ---------------------------------------------------------------------------

#define NCLS  8
#define D     256
#define CHUNK 1024
#define SEG   256
#define EPSF  1e-4f
// sum_c ceil(n_c/CHUNK) <= nrows/CHUNK + NCLS-1 = 128+7 = 135
#define TMAX  144

typedef __bf16 bf16x8 __attribute__((ext_vector_type(8)));
typedef float  f32x4  __attribute__((ext_vector_type(4)));

__device__ __forceinline__ unsigned short f2bf(float f) {
    unsigned int x = __float_as_uint(f);
    x += 0x7fffu + ((x >> 16) & 1u);      // round-to-nearest-even
    return (unsigned short)(x >> 16);
}

// ---- k1a: histogram of row counts per class -------------------------------
__global__ void k_hist(const int* __restrict__ labels, int nlab, int vfac,
                       int* __restrict__ counts) {
    __shared__ int lc[NCLS];
    int t = threadIdx.x;
    if (t < NCLS) lc[t] = 0;
    __syncthreads();
    for (int i = blockIdx.x * blockDim.x + t; i < nlab; i += gridDim.x * blockDim.x)
        atomicAdd(&lc[labels[i] & 7], vfac);
    __syncthreads();
    if (t < NCLS && lc[t]) atomicAdd(&counts[t], lc[t]);
}

// ---- k1b: offsets + cursors ----------------------------------------------
__global__ void k_offsets(const int* __restrict__ counts,
                          int* __restrict__ offsets, int* __restrict__ cursor) {
    if (threadIdx.x == 0) {
        int acc = 0;
        for (int c = 0; c < NCLS; ++c) { offsets[c] = acc; cursor[c] = acc; acc += counts[c]; }
    }
}

// ---- k2: class-sorted row-index array -------------------------------------
__global__ __launch_bounds__(256) void k_idx(
    const int* __restrict__ labels, int nrows, int vfac,
    int* __restrict__ cursor, int* __restrict__ idx)
{
    __shared__ int lcnt[NCLS], lbase[NCLS];
    int t = threadIdx.x;
    int row = blockIdx.x * SEG + t;
    if (t < NCLS) lcnt[t] = 0;
    __syncthreads();
    int c = 0, rk = 0;
    bool ok = (row < nrows);
    if (ok) {
        c = labels[row / vfac] & 7;
        rk = atomicAdd(&lcnt[c], 1);
    }
    __syncthreads();
    if (t < NCLS) lbase[t] = lcnt[t] ? atomicAdd(&cursor[t], lcnt[t]) : 0;
    __syncthreads();
    if (ok) idx[lbase[c] + rk] = row;
}

// ---- k3: per-(chunk, col-half) Gram via MFMA ------------------------------
// WG = 512 threads, 8 waves as 4x2: wave computes 64 rows x 64 cols of the
// 256x128 output half. acc = 4x4 fragments = 64 VGPR/thread.
// LDS K-tile (64 k-rows x 256 feature-cols) stored transposed:
//   quad (ccol, k/4) at byte ccol*128 + ((k&~3)*2 ^ ((ccol&7)<<4))
// Staging thread (kblk=t&15, cblk=t>>4) owns k-rows kblk*4..+3, cols
// cblk*8..+7. Validated conflict-free (rounds 3/4: SQ_LDS_BANK_CONFLICT=0).
__global__ __launch_bounds__(512) void k_gram_g(
    const float* __restrict__ X, const int* __restrict__ idx,
    const int* __restrict__ counts, const int* __restrict__ offsets,
    float* __restrict__ part, float* __restrict__ csums)
{
    __shared__ __align__(16) unsigned char lds[64 * 256 * 2];   // 32 KB

    int t = threadIdx.x;
    int lane = t & 63;
    int w = t >> 6;
    int wrow = w >> 1;          // 0..3 : 64-row band
    int wcol = w & 1;           // 0..1 : 64-col band within the half
    int kblk = t & 15;
    int cblk = t >> 4;

    int nch[NCLS], ofch[NCLS];
    int T = 0;
    for (int c = 0; c < NCLS; ++c) {
        int n = counts[c];
        nch[c] = (n + CHUNK - 1) / CHUNK;
        ofch[c] = T;
        T += nch[c];
    }

    const f32x4 zf = {0.f, 0.f, 0.f, 0.f};

    for (int wk = blockIdx.x; wk < 2 * T; wk += gridDim.x) {
        int item = wk >> 1;
        int half = wk & 1;
        int c = 0;
        while (c < NCLS - 1 && item >= ofch[c + 1]) ++c;
        int chunk = item - ofch[c];
        int base = offsets[c] + chunk * CHUNK;
        int rows = min(CHUNK, counts[c] - chunk * CHUNK);
        int ntiles = (rows + 63) >> 6;

        f32x4 acc[4][4];
        #pragma unroll
        for (int i = 0; i < 4; ++i)
            #pragma unroll
            for (int j = 0; j < 4; ++j)
                #pragma unroll
                for (int r = 0; r < 4; ++r) acc[i][j][r] = 0.f;
        float sumv[8];
        #pragma unroll
        for (int q = 0; q < 8; ++q) sumv[q] = 0.f;

        for (int kt = 0; kt < ntiles; ++kt) {
            // gather + convert + pack (transient regs only; latency hidden
            // by other waves/WGs at ~3 waves/SIMD occupancy)
            uint4 R[4];
            #pragma unroll
            for (int j = 0; j < 4; ++j) {
                int r = kt * 64 + kblk * 4 + j;
                f32x4 fa, fb;
                if (r < rows) {
                    int rid = idx[base + r];
                    const float* rp = X + ((size_t)rid << 8) + cblk * 8;
                    fa = *(const f32x4*)rp;
                    fb = *(const f32x4*)(rp + 4);
                } else { fa = zf; fb = zf; }
                #pragma unroll
                for (int q = 0; q < 4; ++q) { sumv[q] += fa[q]; sumv[4 + q] += fb[q]; }
                unsigned int w0 = (unsigned int)f2bf(fa[0]) | ((unsigned int)f2bf(fa[1]) << 16);
                unsigned int w1 = (unsigned int)f2bf(fa[2]) | ((unsigned int)f2bf(fa[3]) << 16);
                unsigned int w2 = (unsigned int)f2bf(fb[0]) | ((unsigned int)f2bf(fb[1]) << 16);
                unsigned int w3 = (unsigned int)f2bf(fb[2]) | ((unsigned int)f2bf(fb[3]) << 16);
                R[j] = make_uint4(w0, w1, w2, w3);
            }
            __syncthreads();           // previous tile's LDS reads done
            // R -> LDS transposed (4 k-rows packed per 8B write)
            #pragma unroll
            for (int cc = 0; cc < 8; ++cc) {
                int wd = cc >> 1;
                int sh = (cc & 1) * 16;
                unsigned int e0 = (((const unsigned int*)&R[0])[wd] >> sh) & 0xffffu;
                unsigned int e1 = (((const unsigned int*)&R[1])[wd] >> sh) & 0xffffu;
                unsigned int e2 = (((const unsigned int*)&R[2])[wd] >> sh) & 0xffffu;
                unsigned int e3 = (((const unsigned int*)&R[3])[wd] >> sh) & 0xffffu;
                int ccol = cblk * 8 + cc;
                int byt = ccol * 128 + ((kblk * 8) ^ (cc << 4));
                *(uint2*)(lds + byt) = make_uint2(e0 | (e1 << 16), e2 | (e3 << 16));
            }
            __syncthreads();           // staging visible
            // MFMA: 2 k-steps of 32; af loaded per-ti (transient)
            #pragma unroll
            for (int ks = 0; ks < 2; ++ks) {
                int kb2 = ks * 64 + ((lane >> 4) << 4);
                int swz = (lane & 7) << 4;
                bf16x8 bfr[4];
                #pragma unroll
                for (int tj = 0; tj < 4; ++tj) {
                    int ccol = half * 128 + wcol * 64 + tj * 16 + (lane & 15);
                    bfr[tj] = __builtin_bit_cast(bf16x8,
                        *(const uint4*)(lds + ccol * 128 + (kb2 ^ swz)));
                }
                #pragma unroll
                for (int ti = 0; ti < 4; ++ti) {
                    int ccol = wrow * 64 + ti * 16 + (lane & 15);
                    bf16x8 af = __builtin_bit_cast(bf16x8,
                        *(const uint4*)(lds + ccol * 128 + (kb2 ^ swz)));
                    #pragma unroll
                    for (int tj = 0; tj < 4; ++tj)
                        acc[ti][tj] = __builtin_amdgcn_mfma_f32_16x16x32_bf16(
                            af, bfr[tj], acc[ti][tj], 0, 0, 0);
                }
            }
        }

        // flush: plain stores (C/D: col=lane&15, row=(lane>>4)*4+r)
        float* dst = part + (size_t)item * (D * D);
        #pragma unroll
        for (int ti = 0; ti < 4; ++ti) {
            int row0 = wrow * 64 + ti * 16 + ((lane >> 4) << 2);
            #pragma unroll
            for (int tj = 0; tj < 4; ++tj) {
                int col = half * 128 + wcol * 64 + tj * 16 + (lane & 15);
                #pragma unroll
                for (int r = 0; r < 4; ++r)
                    dst[(row0 + r) * D + col] = acc[ti][tj][r];
            }
        }

        // per-chunk column sums (both halves compute; half 0 writes)
        #pragma unroll
        for (int s = 1; s < 16; s <<= 1)
            #pragma unroll
            for (int q = 0; q < 8; ++q)
                sumv[q] += __shfl_xor(sumv[q], s, 64);
        if (half == 0 && (t & 15) == 0) {
            float* cs = csums + (size_t)item * D + cblk * 8;
            #pragma unroll
            for (int q = 0; q < 8; ++q) cs[q] = sumv[q];
        }
        __syncthreads();   // protect LDS before next work-item's staging
    }
}

// ---- k4: reduce per-chunk column sums -> per-class sums -------------------
__global__ __launch_bounds__(256) void k_gsum(
    const float* __restrict__ csums, const int* __restrict__ counts,
    float* __restrict__ gsums)
{
    int c = blockIdx.x;
    int i = threadIdx.x;
    int of = 0;
    for (int cc = 0; cc < c; ++cc) of += (counts[cc] + CHUNK - 1) / CHUNK;
    int nc = (counts[c] + CHUNK - 1) / CHUNK;
    float s = 0.f;
    for (int q = 0; q < nc; ++q) s += csums[(size_t)(of + q) * D + i];
    gsums[c * D + i] = s;
}

// ---- k5: loss epilogue from per-chunk partial Grams -----------------------
__global__ __launch_bounds__(256) void k_loss(
    const float* __restrict__ part, const float* __restrict__ gsums,
    const int* __restrict__ counts, float* __restrict__ out)
{
    __shared__ float red[256];
    int t = threadIdx.x;
    int nch[NCLS], ofch[NCLS];
    int T = 0;
    for (int c = 0; c < NCLS; ++c) {
        int n = counts[c];
        nch[c] = (n + CHUNK - 1) / CHUNK;
        ofch[c] = T;
        T += nch[c];
    }
    float local = 0.f;
    const int total = NCLS * D * D;
    for (int idx = blockIdx.x * blockDim.x + t; idx < total; idx += gridDim.x * blockDim.x) {
        int c = idx >> 16;
        int ij = idx & 0xffff;
        int i = ij >> 8, j = ij & 255;
        const float* p = part + (size_t)ofch[c] * (D * D) + ij;
        float s = 0.f;
        for (int q = 0; q < nch[c]; ++q) s += p[(size_t)q * (D * D)];
        float n  = (float)counts[c];
        float mi = gsums[c * D + i] / n;
        float mj = gsums[c * D + j] / n;
        float cov = (s - n * mi * mj) / (n - 1.f);
        float contrib;
        if (i == j) {
            float sd = sqrtf(cov + EPSF);
            contrib = fmaxf(1.f - sd, 0.f) * (1.f / (float)D);
        } else {
            contrib = cov * cov * (1.f / (float)D);
        }
        local += contrib;
    }
    red[t] = local;
    __syncthreads();
    for (int s = 128; s > 0; s >>= 1) {
        if (t < s) red[t] += red[t + s];
        __syncthreads();
    }
    if (t == 0) atomicAdd(out, red[0]);
}

// ---------------------------------------------------------------------------
extern "C" void kernel_launch(void* const* d_in, const int* in_sizes, int n_in,
                              void* d_out, int out_size, void* d_ws, size_t ws_size,
                              hipStream_t stream)
{
    const float* X      = (const float*)d_in[0];
    const int*   labels = (const int*)d_in[1];
    int nfeat = in_sizes[0];
    int nlab  = in_sizes[1];
    int nrows = nfeat / D;            // 131072
    int vfac  = nrows / nlab;         // 2 views per sample

    char* ws = (char*)d_ws;
    size_t off_idx   = 0;
    size_t sz_idx    = (size_t)nrows * 4;                 // 512 KB
    size_t off_part  = (off_idx + sz_idx + 255) & ~(size_t)255;
    size_t sz_part   = (size_t)TMAX * D * D * 4;          // 37.7 MB
    size_t off_cs    = (off_part + sz_part + 255) & ~(size_t)255;
    size_t sz_cs     = (size_t)TMAX * D * 4;              // 147 KB
    size_t off_gs    = (off_cs + sz_cs + 255) & ~(size_t)255;
    size_t sz_gs     = (size_t)NCLS * D * 4;              // 8 KB
    size_t off_cnt   = (off_gs + sz_gs + 255) & ~(size_t)255;
    size_t off_ofs   = off_cnt + 64;
    size_t off_cur   = off_ofs + 64;

    int*   idx     = (int*)(ws + off_idx);
    float* part    = (float*)(ws + off_part);
    float* csums   = (float*)(ws + off_cs);
    float* gsums   = (float*)(ws + off_gs);
    int*   counts  = (int*)(ws + off_cnt);
    int*   offsets = (int*)(ws + off_ofs);
    int*   cursor  = (int*)(ws + off_cur);

    hipMemsetAsync(counts, 0, 64, stream);
    hipMemsetAsync(d_out, 0, (size_t)out_size * sizeof(float), stream);

    k_hist<<<64, 256, 0, stream>>>(labels, nlab, vfac, counts);
    k_offsets<<<1, 64, 0, stream>>>(counts, offsets, cursor);
    k_idx<<<(nrows + SEG - 1) / SEG, SEG, 0, stream>>>(labels, nrows, vfac, cursor, idx);
    k_gram_g<<<2 * TMAX, 512, 0, stream>>>(X, idx, counts, offsets, part, csums);
    k_gsum<<<NCLS, 256, 0, stream>>>(csums, counts, gsums);
    k_loss<<<512, 256, 0, stream>>>(part, gsums, counts, (float*)d_out);
}

// Round 6
// 124.975 us; speedup vs baseline: 1.7469x; 1.0725x over previous
//
#include <hip/hip_runtime.h>
#include <stdint.h>

// ---------------------------------------------------------------------------
// VarianceMaximizationCovarianceMinimizationLoss on MI355X
//   features [65536,2,256] fp32, labels [65536] int32 -> scalar fp32 loss
// Round 6: col-split gather-Gram (acc=64, spill-free) + cross-tile prefetch:
//   X loads for tile k+1 are issued right after the staging barrier and
//   consumed after the MFMA phase -> HBM latency hides under compute.
// ---------------------------------------------------------------------------

#define NCLS  8
#define D     256
#define CHUNK 1024
#define SEG   256
#define EPSF  1e-4f
// sum_c ceil(n_c/CHUNK) <= nrows/CHUNK + NCLS-1 = 128+7 = 135
#define TMAX  144

typedef __bf16 bf16x8 __attribute__((ext_vector_type(8)));
typedef float  f32x4  __attribute__((ext_vector_type(4)));

__device__ __forceinline__ unsigned short f2bf(float f) {
    unsigned int x = __float_as_uint(f);
    x += 0x7fffu + ((x >> 16) & 1u);      // round-to-nearest-even
    return (unsigned short)(x >> 16);
}

// ---- k1a: histogram of row counts per class -------------------------------
__global__ void k_hist(const int* __restrict__ labels, int nlab, int vfac,
                       int* __restrict__ counts) {
    __shared__ int lc[NCLS];
    int t = threadIdx.x;
    if (t < NCLS) lc[t] = 0;
    __syncthreads();
    for (int i = blockIdx.x * blockDim.x + t; i < nlab; i += gridDim.x * blockDim.x)
        atomicAdd(&lc[labels[i] & 7], vfac);
    __syncthreads();
    if (t < NCLS && lc[t]) atomicAdd(&counts[t], lc[t]);
}

// ---- k1b: offsets + cursors ----------------------------------------------
__global__ void k_offsets(const int* __restrict__ counts,
                          int* __restrict__ offsets, int* __restrict__ cursor) {
    if (threadIdx.x == 0) {
        int acc = 0;
        for (int c = 0; c < NCLS; ++c) { offsets[c] = acc; cursor[c] = acc; acc += counts[c]; }
    }
}

// ---- k2: class-sorted row-index array -------------------------------------
__global__ __launch_bounds__(256) void k_idx(
    const int* __restrict__ labels, int nrows, int vfac,
    int* __restrict__ cursor, int* __restrict__ idx)
{
    __shared__ int lcnt[NCLS], lbase[NCLS];
    int t = threadIdx.x;
    int row = blockIdx.x * SEG + t;
    if (t < NCLS) lcnt[t] = 0;
    __syncthreads();
    int c = 0, rk = 0;
    bool ok = (row < nrows);
    if (ok) {
        c = labels[row / vfac] & 7;
        rk = atomicAdd(&lcnt[c], 1);
    }
    __syncthreads();
    if (t < NCLS) lbase[t] = lcnt[t] ? atomicAdd(&cursor[t], lcnt[t]) : 0;
    __syncthreads();
    if (ok) idx[lbase[c] + rk] = row;
}

// ---- k3: per-(chunk, col-half) Gram via MFMA, pipelined gather ------------
// WG = 512 threads, 8 waves as 4x2: wave computes 64 rows x 64 cols of the
// 256x128 output half. acc = 4x4 fragments = 64 regs/thread.
// LDS K-tile (64 k-rows x 256 feature-cols) stored transposed:
//   quad (ccol, k/4) at byte ccol*128 + ((k&~3)*2 ^ ((ccol&7)<<4))
// Staging thread (kblk=t&15, cblk=t>>4) owns k-rows kblk*4..+3, cols
// cblk*8..+7. Validated conflict-free (rounds 3-5: SQ_LDS_BANK_CONFLICT=0).
__global__ __launch_bounds__(512) void k_gram_g(
    const float* __restrict__ X, const int* __restrict__ idx,
    const int* __restrict__ counts, const int* __restrict__ offsets,
    float* __restrict__ part, float* __restrict__ csums)
{
    __shared__ __align__(16) unsigned char lds[64 * 256 * 2];   // 32 KB

    int t = threadIdx.x;
    int lane = t & 63;
    int w = t >> 6;
    int wrow = w >> 1;          // 0..3 : 64-row band
    int wcol = w & 1;           // 0..1 : 64-col band within the half
    int kblk = t & 15;
    int cblk = t >> 4;

    int nch[NCLS], ofch[NCLS];
    int T = 0;
    for (int c = 0; c < NCLS; ++c) {
        int n = counts[c];
        nch[c] = (n + CHUNK - 1) / CHUNK;
        ofch[c] = T;
        T += nch[c];
    }

    const f32x4 zf = {0.f, 0.f, 0.f, 0.f};

    for (int wk = blockIdx.x; wk < 2 * T; wk += gridDim.x) {
        int item = wk >> 1;
        int half = wk & 1;
        int c = 0;
        while (c < NCLS - 1 && item >= ofch[c + 1]) ++c;
        int chunk = item - ofch[c];
        int base = offsets[c] + chunk * CHUNK;
        int rows = min(CHUNK, counts[c] - chunk * CHUNK);
        int ntiles = (rows + 63) >> 6;

        f32x4 acc[4][4];
        #pragma unroll
        for (int i = 0; i < 4; ++i)
            #pragma unroll
            for (int j = 0; j < 4; ++j)
                #pragma unroll
                for (int r = 0; r < 4; ++r) acc[i][j][r] = 0.f;
        float sumv[8];
        #pragma unroll
        for (int q = 0; q < 8; ++q) sumv[q] = 0.f;

        uint4 R[4];        // packed bf16, current tile (4 rows x 8 cols/thread)
        f32x4 fa[4], fb[4];
        int idn[4];        // row ids for the NEXT tile to issue

        // ---- prologue: tile-0 ids -> X loads -> tile-1 ids -> convert -----
        #pragma unroll
        for (int j = 0; j < 4; ++j) {
            int r = kblk * 4 + j;
            idn[j] = (r < rows) ? idx[base + r] : 0;
        }
        #pragma unroll
        for (int j = 0; j < 4; ++j) {
            int r = kblk * 4 + j;
            if (r < rows) {
                const float* rp = X + ((size_t)idn[j] << 8) + cblk * 8;
                fa[j] = *(const f32x4*)rp;
                fb[j] = *(const f32x4*)(rp + 4);
            } else { fa[j] = zf; fb[j] = zf; }
        }
        #pragma unroll
        for (int j = 0; j < 4; ++j) {
            int r = 64 + kblk * 4 + j;
            idn[j] = (r < rows) ? idx[base + r] : 0;
        }
        #pragma unroll
        for (int j = 0; j < 4; ++j) {
            #pragma unroll
            for (int q = 0; q < 4; ++q) { sumv[q] += fa[j][q]; sumv[4 + q] += fb[j][q]; }
            unsigned int w0 = (unsigned int)f2bf(fa[j][0]) | ((unsigned int)f2bf(fa[j][1]) << 16);
            unsigned int w1 = (unsigned int)f2bf(fa[j][2]) | ((unsigned int)f2bf(fa[j][3]) << 16);
            unsigned int w2 = (unsigned int)f2bf(fb[j][0]) | ((unsigned int)f2bf(fb[j][1]) << 16);
            unsigned int w3 = (unsigned int)f2bf(fb[j][2]) | ((unsigned int)f2bf(fb[j][3]) << 16);
            R[j] = make_uint4(w0, w1, w2, w3);
        }

        for (int kt = 0; kt < ntiles; ++kt) {
            __syncthreads();           // previous tile's LDS reads done
            // R -> LDS transposed (4 k-rows packed per 8B write)
            #pragma unroll
            for (int cc = 0; cc < 8; ++cc) {
                int wd = cc >> 1;
                int sh = (cc & 1) * 16;
                unsigned int e0 = (((const unsigned int*)&R[0])[wd] >> sh) & 0xffffu;
                unsigned int e1 = (((const unsigned int*)&R[1])[wd] >> sh) & 0xffffu;
                unsigned int e2 = (((const unsigned int*)&R[2])[wd] >> sh) & 0xffffu;
                unsigned int e3 = (((const unsigned int*)&R[3])[wd] >> sh) & 0xffffu;
                int ccol = cblk * 8 + cc;
                int byt = ccol * 128 + ((kblk * 8) ^ (cc << 4));
                *(uint2*)(lds + byt) = make_uint2(e0 | (e1 << 16), e2 | (e3 << 16));
            }
            __syncthreads();           // staging visible

            // issue NEXT tile's X loads now: they stay in flight under the
            // MFMA phase (first use = convert, after the MFMAs)
            bool more = (kt + 1 < ntiles);
            if (more) {
                #pragma unroll
                for (int j = 0; j < 4; ++j) {
                    int r = (kt + 1) * 64 + kblk * 4 + j;
                    if (r < rows) {
                        const float* rp = X + ((size_t)idn[j] << 8) + cblk * 8;
                        fa[j] = *(const f32x4*)rp;
                        fb[j] = *(const f32x4*)(rp + 4);
                    } else { fa[j] = zf; fb[j] = zf; }
                }
            }
            // ids for tile kt+2 (L2-resident, consumed next iteration)
            int idf[4];
            #pragma unroll
            for (int j = 0; j < 4; ++j) {
                int r = (kt + 2) * 64 + kblk * 4 + j;
                idf[j] = (more && r < rows) ? idx[base + r] : 0;
            }

            // MFMA: 2 k-steps of 32; af loaded per-ti (transient)
            #pragma unroll
            for (int ks = 0; ks < 2; ++ks) {
                int kb2 = ks * 64 + ((lane >> 4) << 4);
                int swz = (lane & 7) << 4;
                bf16x8 bfr[4];
                #pragma unroll
                for (int tj = 0; tj < 4; ++tj) {
                    int ccol = half * 128 + wcol * 64 + tj * 16 + (lane & 15);
                    bfr[tj] = __builtin_bit_cast(bf16x8,
                        *(const uint4*)(lds + ccol * 128 + (kb2 ^ swz)));
                }
                #pragma unroll
                for (int ti = 0; ti < 4; ++ti) {
                    int ccol = wrow * 64 + ti * 16 + (lane & 15);
                    bf16x8 af = __builtin_bit_cast(bf16x8,
                        *(const uint4*)(lds + ccol * 128 + (kb2 ^ swz)));
                    #pragma unroll
                    for (int tj = 0; tj < 4; ++tj)
                        acc[ti][tj] = __builtin_amdgcn_mfma_f32_16x16x32_bf16(
                            af, bfr[tj], acc[ti][tj], 0, 0, 0);
                }
            }

            // convert next tile (first consume of the in-flight loads) + sums
            if (more) {
                #pragma unroll
                for (int j = 0; j < 4; ++j) {
                    #pragma unroll
                    for (int q = 0; q < 4; ++q) { sumv[q] += fa[j][q]; sumv[4 + q] += fb[j][q]; }
                    unsigned int w0 = (unsigned int)f2bf(fa[j][0]) | ((unsigned int)f2bf(fa[j][1]) << 16);
                    unsigned int w1 = (unsigned int)f2bf(fa[j][2]) | ((unsigned int)f2bf(fa[j][3]) << 16);
                    unsigned int w2 = (unsigned int)f2bf(fb[j][0]) | ((unsigned int)f2bf(fb[j][1]) << 16);
                    unsigned int w3 = (unsigned int)f2bf(fb[j][2]) | ((unsigned int)f2bf(fb[j][3]) << 16);
                    R[j] = make_uint4(w0, w1, w2, w3);
                }
                #pragma unroll
                for (int j = 0; j < 4; ++j) idn[j] = idf[j];
            }
        }

        // flush: plain stores (C/D: col=lane&15, row=(lane>>4)*4+r)
        float* dst = part + (size_t)item * (D * D);
        #pragma unroll
        for (int ti = 0; ti < 4; ++ti) {
            int row0 = wrow * 64 + ti * 16 + ((lane >> 4) << 2);
            #pragma unroll
            for (int tj = 0; tj < 4; ++tj) {
                int col = half * 128 + wcol * 64 + tj * 16 + (lane & 15);
                #pragma unroll
                for (int r = 0; r < 4; ++r)
                    dst[(row0 + r) * D + col] = acc[ti][tj][r];
            }
        }

        // per-chunk column sums (both halves compute; half 0 writes)
        #pragma unroll
        for (int s = 1; s < 16; s <<= 1)
            #pragma unroll
            for (int q = 0; q < 8; ++q)
                sumv[q] += __shfl_xor(sumv[q], s, 64);
        if (half == 0 && (t & 15) == 0) {
            float* cs = csums + (size_t)item * D + cblk * 8;
            #pragma unroll
            for (int q = 0; q < 8; ++q) cs[q] = sumv[q];
        }
        __syncthreads();   // protect LDS before next work-item's staging
    }
}

// ---- k4: reduce per-chunk column sums -> per-class sums -------------------
__global__ __launch_bounds__(256) void k_gsum(
    const float* __restrict__ csums, const int* __restrict__ counts,
    float* __restrict__ gsums)
{
    int c = blockIdx.x;
    int i = threadIdx.x;
    int of = 0;
    for (int cc = 0; cc < c; ++cc) of += (counts[cc] + CHUNK - 1) / CHUNK;
    int nc = (counts[c] + CHUNK - 1) / CHUNK;
    float s = 0.f;
    for (int q = 0; q < nc; ++q) s += csums[(size_t)(of + q) * D + i];
    gsums[c * D + i] = s;
}

// ---- k5: loss epilogue from per-chunk partial Grams -----------------------
__global__ __launch_bounds__(256) void k_loss(
    const float* __restrict__ part, const float* __restrict__ gsums,
    const int* __restrict__ counts, float* __restrict__ out)
{
    __shared__ float red[256];
    int t = threadIdx.x;
    int nch[NCLS], ofch[NCLS];
    int T = 0;
    for (int c = 0; c < NCLS; ++c) {
        int n = counts[c];
        nch[c] = (n + CHUNK - 1) / CHUNK;
        ofch[c] = T;
        T += nch[c];
    }
    float local = 0.f;
    const int total = NCLS * D * D;
    for (int idx = blockIdx.x * blockDim.x + t; idx < total; idx += gridDim.x * blockDim.x) {
        int c = idx >> 16;
        int ij = idx & 0xffff;
        int i = ij >> 8, j = ij & 255;
        const float* p = part + (size_t)ofch[c] * (D * D) + ij;
        float s = 0.f;
        for (int q = 0; q < nch[c]; ++q) s += p[(size_t)q * (D * D)];
        float n  = (float)counts[c];
        float mi = gsums[c * D + i] / n;
        float mj = gsums[c * D + j] / n;
        float cov = (s - n * mi * mj) / (n - 1.f);
        float contrib;
        if (i == j) {
            float sd = sqrtf(cov + EPSF);
            contrib = fmaxf(1.f - sd, 0.f) * (1.f / (float)D);
        } else {
            contrib = cov * cov * (1.f / (float)D);
        }
        local += contrib;
    }
    red[t] = local;
    __syncthreads();
    for (int s = 128; s > 0; s >>= 1) {
        if (t < s) red[t] += red[t + s];
        __syncthreads();
    }
    if (t == 0) atomicAdd(out, red[0]);
}

// ---------------------------------------------------------------------------
extern "C" void kernel_launch(void* const* d_in, const int* in_sizes, int n_in,
                              void* d_out, int out_size, void* d_ws, size_t ws_size,
                              hipStream_t stream)
{
    const float* X      = (const float*)d_in[0];
    const int*   labels = (const int*)d_in[1];
    int nfeat = in_sizes[0];
    int nlab  = in_sizes[1];
    int nrows = nfeat / D;            // 131072
    int vfac  = nrows / nlab;         // 2 views per sample

    char* ws = (char*)d_ws;
    size_t off_idx   = 0;
    size_t sz_idx    = (size_t)nrows * 4;                 // 512 KB
    size_t off_part  = (off_idx + sz_idx + 255) & ~(size_t)255;
    size_t sz_part   = (size_t)TMAX * D * D * 4;          // 37.7 MB
    size_t off_cs    = (off_part + sz_part + 255) & ~(size_t)255;
    size_t sz_cs     = (size_t)TMAX * D * 4;              // 147 KB
    size_t off_gs    = (off_cs + sz_cs + 255) & ~(size_t)255;
    size_t sz_gs     = (size_t)NCLS * D * 4;              // 8 KB
    size_t off_cnt   = (off_gs + sz_gs + 255) & ~(size_t)255;
    size_t off_ofs   = off_cnt + 64;
    size_t off_cur   = off_ofs + 64;

    int*   idx     = (int*)(ws + off_idx);
    float* part    = (float*)(ws + off_part);
    float* csums   = (float*)(ws + off_cs);
    float* gsums   = (float*)(ws + off_gs);
    int*   counts  = (int*)(ws + off_cnt);
    int*   offsets = (int*)(ws + off_ofs);
    int*   cursor  = (int*)(ws + off_cur);

    hipMemsetAsync(counts, 0, 64, stream);
    hipMemsetAsync(d_out, 0, (size_t)out_size * sizeof(float), stream);

    k_hist<<<64, 256, 0, stream>>>(labels, nlab, vfac, counts);
    k_offsets<<<1, 64, 0, stream>>>(counts, offsets, cursor);
    k_idx<<<(nrows + SEG - 1) / SEG, SEG, 0, stream>>>(labels, nrows, vfac, cursor, idx);
    k_gram_g<<<2 * TMAX, 512, 0, stream>>>(X, idx, counts, offsets, part, csums);
    k_gsum<<<NCLS, 256, 0, stream>>>(csums, counts, gsums);
    k_loss<<<512, 256, 0, stream>>>(part, gsums, counts, (float*)d_out);
}